// Round 17
// baseline (577.434 us; speedup 1.0000x reference)
//
#include <hip/hip_runtime.h>
#include <hip/hip_bf16.h>
#include <cstdint>
#include <cstddef>

// CascadeAttention MI355X — v16: v15 (360.8us) + fused prep kernel (bias gather
// + both weight splits + head-0 qkv in ONE dispatch, block-range dispatch) +
// s_setprio(1) around k_head MFMA clusters (T5 probe; waves phase-diverge).

#define NH    8
#define KD    16
#define DV    32
#define CH    32
#define QKVO  64
#define DIMC  256
#define NTOK  392
#define NPAD  448
#define BSZ   128
#define EPSV  1e-5f
#define SCL2  0.3606737602222409f   // 0.25 * log2(e)
#define LOG2E 1.4426950408889634f
#define MQ    98                    // ceil(392/4)

// k_prep block-range bounds
#define NB_BIAS 4802                // 8*98*392*4 / 256
#define NB_WSP  256                 // 65536 / 256
#define NB_WSPQ 64                  // 16384 / 256
#define NB_QKV0 896                 // 7 * 128

typedef float f32x4 __attribute__((ext_vector_type(4)));
typedef short bf16x8 __attribute__((ext_vector_type(8)));
typedef unsigned int u32x4 __attribute__((ext_vector_type(4)));
typedef unsigned int u32x2 __attribute__((ext_vector_type(2)));

__device__ inline unsigned rne_bf16_bits(float x) {
  unsigned u = __float_as_uint(x);
  return (u + 0x7fffu + ((u >> 16) & 1u)) >> 16;
}
__device__ inline unsigned cvt_pk(float a, float b) {  // lo16=bf16(a), hi16=bf16(b)
  unsigned r;
  asm("v_cvt_pk_bf16_f32 %0, %1, %2" : "=v"(r) : "v"(a), "v"(b));
  return r;
}
__device__ inline float b2f_lo(unsigned w) { return __uint_as_float(w << 16); }
__device__ inline float b2f_hi(unsigned w) { return __uint_as_float(w & 0xffff0000u); }

// ---------------- fused prep: bias gather | W splits | head-0 qkv ----------
__global__ __launch_bounds__(256) void k_prep(
    const float* __restrict__ rpb, const int* __restrict__ rel,
    float* __restrict__ biasM,
    const float* __restrict__ Wp, short* __restrict__ Whi, short* __restrict__ Wlo,
    const float* __restrict__ Wq, short* __restrict__ Wqhi, short* __restrict__ Wqlo,
    const float* __restrict__ x, const float* __restrict__ G,
    const float* __restrict__ Bp, const float* __restrict__ Mp,
    const float* __restrict__ Vp,
    float* __restrict__ qb0, short* __restrict__ kT0, short* __restrict__ vb0,
    short* __restrict__ kT1, short* __restrict__ vb1) {
  int blk = blockIdx.x;
  int t = threadIdx.x;

  if (blk < NB_BIAS) {
    // ---- biasM[h][mq][n][j] = rpb[rel[n][4mq+j]][h] * log2e ----
    int idx = blk * 256 + t;
    if (idx >= NH * MQ * NTOK * 4) return;
    int j = idx & 3;
    int r1 = idx >> 2;
    int n = r1 % NTOK;
    int r2 = r1 / NTOK;
    int mq = r2 % MQ;
    int h = r2 / MQ;
    int m = min(4 * mq + j, NTOK - 1);
    biasM[idx] = rpb[rel[n * NTOK + m] * NH + h] * LOG2E;
    return;
  }
  if (blk < NB_BIAS + NB_WSP) {
    int i = (blk - NB_BIAS) * 256 + t;
    float v = Wp[i];
    unsigned u = __float_as_uint(v) & 0xffff0000u;
    Whi[i] = (short)(u >> 16);
    Wlo[i] = (short)rne_bf16_bits(v - __uint_as_float(u));
    return;
  }
  if (blk < NB_BIAS + NB_WSP + NB_WSPQ) {
    int i = (blk - NB_BIAS - NB_WSP) * 256 + t;
    float v = Wq[i];
    unsigned u = __float_as_uint(v) & 0xffff0000u;
    Wqhi[i] = (short)(u >> 16);
    Wqlo[i] = (short)rne_bf16_bits(v - __uint_as_float(u));
    return;
  }

  // ---- head-0 qkv + zero-init of ping-pong padding ----
  {
    int idq = blk - (NB_BIAS + NB_WSP + NB_WSPQ);
    int qt = idq % 7, b = idq / 7;
    int n = qt * 64 + (t & 63);
    int w = t >> 6;
    int o0 = __builtin_amdgcn_readfirstlane(w * 16);
    int nc = min(n, NTOK - 1);

    const float* xp = x + (size_t)b * DIMC * NTOK + nc;
    float f[CH];
#pragma unroll
    for (int c = 0; c < CH; ++c) f[c] = xp[(size_t)c * NTOK];

    float acc[16];
#pragma unroll
    for (int oi = 0; oi < 16; ++oi) acc[oi] = 0.f;
#pragma unroll
    for (int c = 0; c < CH; ++c) {
      float fv = f[c];
#pragma unroll
      for (int oi = 0; oi < 16; ++oi) acc[oi] += Wq[(o0 + oi) * CH + c] * fv;
    }
    float r[16];
#pragma unroll
    for (int oi = 0; oi < 16; ++oi) {
      int o = o0 + oi;
      float s = G[o] * rsqrtf(Vp[o] + EPSV);
      float sh = Bp[o] - Mp[o] * s;
      r[oi] = acc[oi] * s + sh;
    }

    if (w == 0) {
      if (n < NTOK) {
#pragma unroll
        for (int oi = 0; oi < 16; ++oi)
          qb0[((size_t)b * KD + oi) * NTOK + n] = r[oi];
      }
    } else if (w == 1) {
      unsigned wh[8], wl[8];
#pragma unroll
      for (int i = 0; i < 8; ++i) wh[i] = cvt_pk(r[2 * i], r[2 * i + 1]);
#pragma unroll
      for (int i = 0; i < 8; ++i)
        wl[i] = cvt_pk(r[2 * i] - b2f_lo(wh[i]), r[2 * i + 1] - b2f_hi(wh[i]));
      short* row = kT0 + ((size_t)b * NPAD + n) * 32;
      *(u32x4*)&row[0]  = (u32x4){wh[0], wh[1], wh[2], wh[3]};
      *(u32x4*)&row[8]  = (u32x4){wh[4], wh[5], wh[6], wh[7]};
      *(u32x4*)&row[16] = (u32x4){wl[0], wl[1], wl[2], wl[3]};
      *(u32x4*)&row[24] = (u32x4){wl[4], wl[5], wl[6], wl[7]};
      if (n >= NTOK) {
        short* row1 = kT1 + ((size_t)b * NPAD + n) * 32;
#pragma unroll
        for (int p = 0; p < 4; ++p) *(u32x4*)&row1[p * 8] = (u32x4){0, 0, 0, 0};
      }
    } else {
      int vc0 = (w - 2) * 16;
#pragma unroll
      for (int oi = 0; oi < 16; ++oi)
        vb0[((size_t)b * DV + vc0 + oi) * NPAD + n] = (short)rne_bf16_bits(r[oi]);
      if (n >= NTOK) {
#pragma unroll
        for (int oi = 0; oi < 16; ++oi)
          vb1[((size_t)b * DV + vc0 + oi) * NPAD + n] = 0;
      }
    }
  }
}

// ---------------- fused per-head kernel (XCD-swizzled 1-D grid) ------------
__global__ __launch_bounds__(256, 8) void k_head(int head,
    const float* __restrict__ x,
    const float* __restrict__ qbC, const short* __restrict__ kTC,
    const short* __restrict__ vbC, const float* __restrict__ biasM,
    const float* __restrict__ DW, const float* __restrict__ dG,
    const float* __restrict__ dB, const float* __restrict__ dM,
    const float* __restrict__ dV,
    const short* __restrict__ Wqhi, const short* __restrict__ Wqlo,
    const float* __restrict__ qG, const float* __restrict__ qBp,
    const float* __restrict__ qM, const float* __restrict__ qV,
    unsigned* __restrict__ catB, float* __restrict__ qbN,
    short* __restrict__ kTN, short* __restrict__ vbN) {
  __shared__ float wdw[432];
  __shared__ float qstage[16][17];
  __shared__ __align__(16) float ubuf[2304];  // halo[16][133] / Pbuf[4][576] / oP[4][32][17]
  __shared__ float lM[4][16];
  __shared__ float oF[32][17];
  __shared__ float xs[32][17];

  int t = threadIdx.x;
  int id = blockIdx.x;
  int r8 = id & 7;
  int jd = id >> 3;
  int qt = jd % 25;
  int b = 8 * (jd / 25) + r8;
  int w = t >> 6, l = t & 63;
  int ln = l & 15, g = l >> 4;
  int tok16 = t & 15, gr = t >> 4;
  int koff = ((g >> 1) << 4) + ((g & 1) << 3);

  // ---- phase A: stage dwconv weights + q halo, conv + BN + SCL2 ----
  {
    float (*hs)[133] = (float(*)[133])ubuf;
    for (int i = t; i < 432; i += 256) wdw[i] = DW[head * 432 + i];
    const float* qpb = qbC + (size_t)b * KD * NTOK;
    int nlo = qt * 16 - 57;
    for (int i = t; i < 16 * 130; i += 256) {
      int c = i / 130, r = i - c * 130;
      int n = nlo + r;
      hs[c][r] = (n >= 0 && n < NTOK) ? qpb[(size_t)c * NTOK + n] : 0.f;
    }
    __syncthreads();
    int tokg = qt * 16 + tok16;
    int tkc = min(tokg, NTOK - 1);
    int z = tkc / 49, rm = tkc - z * 49, y = rm / 7, xx = rm - y * 7;
    const float* wt = &wdw[gr * 27];
    float a = 0.f;
#pragma unroll
    for (int dz = 0; dz < 3; ++dz) {
      int zz = z + dz - 1;
      if (zz < 0 || zz >= 8) continue;
#pragma unroll
      for (int dy = 0; dy < 3; ++dy) {
        int yy = y + dy - 1;
        if (yy < 0 || yy >= 7) continue;
#pragma unroll
        for (int dx = 0; dx < 3; ++dx) {
          int xw = xx + dx - 1;
          if (xw < 0 || xw >= 7) continue;
          a += wt[dz * 9 + dy * 3 + dx] * hs[gr][zz * 49 + yy * 7 + xw - nlo];
        }
      }
    }
    float s = dG[head * KD + gr] * rsqrtf(dV[head * KD + gr] + EPSV);
    float sh = dB[head * KD + gr] - dM[head * KD + gr] * s;
    __syncthreads();            // all halo reads done before ubuf reuse
    qstage[gr][tok16] = (a * s + sh) * SCL2;
  }
  __syncthreads();

  // ---- Q fragments ----
  bf16x8 qB1, qB2;
  {
    float qv[8];
#pragma unroll
    for (int j2 = 0; j2 < 8; ++j2) qv[j2] = qstage[8 * (g & 1) + j2][ln];
    u32x4 hw;
#pragma unroll
    for (int i = 0; i < 4; ++i) hw[i] = cvt_pk(qv[2 * i], qv[2 * i + 1]);
    qB1 = *(bf16x8*)&hw;
    if (g < 2) {
      u32x4 lw;
#pragma unroll
      for (int i = 0; i < 4; ++i)
        lw[i] = cvt_pk(qv[2 * i] - b2f_lo(hw[i]), qv[2 * i + 1] - b2f_hi(hw[i]));
      qB2 = *(bf16x8*)&lw;
    } else {
#pragma unroll
      for (int j2 = 0; j2 < 8; ++j2) qB2[j2] = 0;
    }
  }

  int tokq = qt * 16 + ln;
  int tqc = min(tokq, NTOK - 1);
  const short* kbase = kTC + (size_t)b * NPAD * 32;
  const short* vbase = vbC + (size_t)b * DV * NPAD;
  const float* bb = biasM + ((size_t)head * MQ * NTOK + tqc) * 4;
  unsigned* pb = (unsigned*)ubuf + w * 576;

  f32x4 oacc[2];
#pragma unroll
  for (int ct = 0; ct < 2; ++ct) oacc[ct] = (f32x4){0.f, 0.f, 0.f, 0.f};
  float lsum = 0.f;

  // ---- phase B: attn over m-tiles {w, w+4} ----
  for (int mt = w; mt < 7; mt += 4) {
    int m0 = mt * 64;
    bf16x8 aK[4];
#pragma unroll
    for (int ms = 0; ms < 4; ++ms)
      aK[ms] = *(const bf16x8*)&kbase[(size_t)(m0 + 16 * ms + ln) * 32 + koff];
    f32x4 bv[4];
#pragma unroll
    for (int ms = 0; ms < 4; ++ms) {
      int mq = min((m0 + 16 * ms + 4 * g) >> 2, MQ - 1);
      bv[ms] = *(const f32x4*)&bb[(size_t)mq * (NTOK * 4)];
    }
    bf16x8 aV[4];
#pragma unroll
    for (int ch = 0; ch < 2; ++ch)
#pragma unroll
      for (int ct = 0; ct < 2; ++ct)
        aV[ch * 2 + ct] = *(const bf16x8*)&vbase[(size_t)(16 * ct + ln) * NPAD
                                                 + m0 + 32 * ch + 8 * g];
    f32x4 S[4];
    __builtin_amdgcn_s_setprio(1);
#pragma unroll
    for (int ms = 0; ms < 4; ++ms) {
      f32x4 a = __builtin_amdgcn_mfma_f32_16x16x32_bf16(aK[ms], qB1, bv[ms], 0, 0, 0);
      S[ms] = __builtin_amdgcn_mfma_f32_16x16x32_bf16(aK[ms], qB2, a, 0, 0, 0);
    }
    __builtin_amdgcn_s_setprio(0);
#pragma unroll
    for (int ms = 0; ms < 4; ++ms) {
      int mk = m0 + 16 * ms + 4 * g;
      float p[4];
#pragma unroll
      for (int r = 0; r < 4; ++r) {
        float sv = fminf(S[ms][r], 96.f);
        if (mk + r >= NTOK) sv = -1e30f;
        p[r] = __builtin_amdgcn_exp2f(sv);
        lsum += p[r];
      }
      u32x2 pw = (u32x2){cvt_pk(p[0], p[1]), cvt_pk(p[2], p[3])};
      *(u32x2*)&pb[ln * 36 + 8 * ms + 2 * g] = pw;
    }
    __builtin_amdgcn_s_setprio(1);
#pragma unroll
    for (int ch = 0; ch < 2; ++ch) {
      u32x4 pk4 = *(const u32x4*)&pb[ln * 36 + 16 * ch + 4 * g];
      bf16x8 pf = *(bf16x8*)&pk4;
#pragma unroll
      for (int ct = 0; ct < 2; ++ct)
        oacc[ct] = __builtin_amdgcn_mfma_f32_16x16x32_bf16(aV[ch * 2 + ct], pf, oacc[ct], 0, 0, 0);
    }
    __builtin_amdgcn_s_setprio(0);
  }

  // ---- phase C: partial reduce + merge (oP aliases ubuf -> sync first) ----
  __syncthreads();
  float (*oP)[32][17] = (float(*)[32][17])ubuf;
  lsum += __shfl_xor(lsum, 16);
  lsum += __shfl_xor(lsum, 32);
#pragma unroll
  for (int ct = 0; ct < 2; ++ct)
#pragma unroll
    for (int r = 0; r < 4; ++r) oP[w][16 * ct + 4 * g + r][ln] = oacc[ct][r];
  if (g == 0) lM[w][ln] = lsum;
  __syncthreads();

  // ---- phase D: finalize, catB store, x stage ----
  {
    int tokg = qt * 16 + tok16;
    float lt = lM[0][tok16] + lM[1][tok16] + lM[2][tok16] + lM[3][tok16];
    float inv = 1.f / fmaxf(lt, 1e-30f);
    int c0 = 2 * gr, c1 = c0 + 1;
    float a0 = (oP[0][c0][tok16] + oP[1][c0][tok16] + oP[2][c0][tok16] + oP[3][c0][tok16]) * inv;
    float a1 = (oP[0][c1][tok16] + oP[1][c1][tok16] + oP[2][c1][tok16] + oP[3][c1][tok16]) * inv;
    oF[c0][tok16] = a0;
    oF[c1][tok16] = a1;
    if (tokg < NTOK)
      catB[((size_t)b * 128 + head * 16 + gr) * NTOK + tokg] =
          cvt_pk(fmaxf(a0, 0.f), fmaxf(a1, 0.f));
    if (head < 7) {
      for (int i = t; i < 512; i += 256) {
        int c = i >> 4, tk = i & 15;
        int tg = min(qt * 16 + tk, NTOK - 1);
        xs[c][tk] = x[((size_t)b * DIMC + (head + 1) * CH + c) * NTOK + tg];
      }
    }
  }
  __syncthreads();

  // ---- phase E: next-head qkv via MFMA (3-term hi/lo) ----
  if (head < 7) {
    const short* wqh = Wqhi + ((size_t)(head + 1) * QKVO + 16 * w + ln) * CH + 8 * g;
    const short* wql = Wqlo + ((size_t)(head + 1) * QKVO + 16 * w + ln) * CH + 8 * g;
    bf16x8 Ah = *(const bf16x8*)wqh;
    bf16x8 Al = *(const bf16x8*)wql;
    float f8[8];
#pragma unroll
    for (int j2 = 0; j2 < 8; ++j2) f8[j2] = oF[8 * g + j2][ln] + xs[8 * g + j2][ln];
    u32x4 bh, blw;
#pragma unroll
    for (int i = 0; i < 4; ++i) {
      bh[i] = cvt_pk(f8[2 * i], f8[2 * i + 1]);
      blw[i] = cvt_pk(f8[2 * i] - b2f_lo(bh[i]), f8[2 * i + 1] - b2f_hi(bh[i]));
    }
    bf16x8 Bh = *(bf16x8*)&bh;
    bf16x8 Bl = *(bf16x8*)&blw;
    f32x4 acc = (f32x4){0.f, 0.f, 0.f, 0.f};
    acc = __builtin_amdgcn_mfma_f32_16x16x32_bf16(Ah, Bh, acc, 0, 0, 0);
    acc = __builtin_amdgcn_mfma_f32_16x16x32_bf16(Ah, Bl, acc, 0, 0, 0);
    acc = __builtin_amdgcn_mfma_f32_16x16x32_bf16(Al, Bh, acc, 0, 0, 0);
    float r4[4];
#pragma unroll
    for (int r = 0; r < 4; ++r) {
      int o = 16 * w + 4 * g + r;
      int idx = (head + 1) * QKVO + o;
      float s = qG[idx] * rsqrtf(qV[idx] + EPSV);
      float sh = qBp[idx] - qM[idx] * s;
      r4[r] = acc[r] * s + sh;
    }
    int tokg = qt * 16 + ln;
    if (tokg < NTOK) {
      if (w == 0) {             // q channels 4g..4g+3, fp32 [c][n]
#pragma unroll
        for (int r = 0; r < 4; ++r)
          qbN[((size_t)b * KD + 4 * g + r) * NTOK + tokg] = r4[r];
      } else if (w == 1) {      // k channels 4g..4g+3 -> packed row
        unsigned h0 = cvt_pk(r4[0], r4[1]), h1 = cvt_pk(r4[2], r4[3]);
        unsigned l0 = cvt_pk(r4[0] - b2f_lo(h0), r4[1] - b2f_hi(h0));
        unsigned l1 = cvt_pk(r4[2] - b2f_lo(h1), r4[3] - b2f_hi(h1));
        short* row = kTN + ((size_t)b * NPAD + tokg) * 32;
        *(u32x2*)&row[4 * g]      = (u32x2){h0, h1};
        *(u32x2*)&row[16 + 4 * g] = (u32x2){l0, l1};
      } else {                  // v channels 16(w-2)+4g..+3, bf16 [c][n]
        int vc0 = 16 * (w - 2) + 4 * g;
#pragma unroll
        for (int r = 0; r < 4; ++r)
          vbN[((size_t)b * DV + vc0 + r) * NPAD + tokg] = (short)rne_bf16_bits(r4[r]);
      }
    }
  }
}

// ---------------- proj: o-split (128 o x 64 n), XCD-pinned, dbuf -----------
__global__ __launch_bounds__(256, 4) void k_proj7(const unsigned* __restrict__ catB,
    const short* __restrict__ Whi, const short* __restrict__ Wlo,
    const float* __restrict__ G, const float* __restrict__ Bp,
    const float* __restrict__ Mp, const float* __restrict__ Vp,
    float* __restrict__ out) {
  int t = threadIdx.x;
  int id = blockIdx.x;
  int r8 = id & 7;
  int jd = id >> 3;
  int rem = jd % 14;
  int b = 8 * (jd / 14) + r8;
  int nt = rem >> 1, oh = rem & 1;
  int w = t >> 6, l = t & 63;
  int ln = l & 15, g = l >> 4;
  int n0 = nt * 64;
  int ob = oh * 128 + 32 * w;
  int ntk[4];
#pragma unroll
  for (int ns = 0; ns < 4; ++ns) ntk[ns] = min(n0 + 16 * ns + ln, NTOK - 1);
  const unsigned* xb = catB + (size_t)b * 128 * NTOK;

  f32x4 acc[2][4];
#pragma unroll
  for (int i = 0; i < 2; ++i)
#pragma unroll
    for (int j = 0; j < 4; ++j) acc[i][j] = (f32x4){0.f, 0.f, 0.f, 0.f};

  unsigned rb[4][4];
  bf16x8 wh[2], wl[2];
  {
#pragma unroll
    for (int ns = 0; ns < 4; ++ns)
#pragma unroll
      for (int i = 0; i < 4; ++i)
        rb[ns][i] = xb[(size_t)(4 * g + i) * NTOK + ntk[ns]];
#pragma unroll
    for (int ot = 0; ot < 2; ++ot) {
      size_t wo = (size_t)(ob + 16 * ot + ln) * DIMC + 8 * g;
      wh[ot] = *(const bf16x8*)&Whi[wo];
      wl[ot] = *(const bf16x8*)&Wlo[wo];
    }
  }

#pragma unroll 1
  for (int c8 = 0; c8 < 8; ++c8) {
    unsigned rbn[4][4];
    bf16x8 whn[2], wln[2];
    {
      int cpn = ((c8 + 1) & 7) * 16 + 4 * g;
#pragma unroll
      for (int ns = 0; ns < 4; ++ns)
#pragma unroll
        for (int i = 0; i < 4; ++i)
          rbn[ns][i] = xb[(size_t)(cpn + i) * NTOK + ntk[ns]];
      int cwn = ((c8 + 1) & 7) * 32 + 8 * g;
#pragma unroll
      for (int ot = 0; ot < 2; ++ot) {
        size_t wo = (size_t)(ob + 16 * ot + ln) * DIMC + cwn;
        whn[ot] = *(const bf16x8*)&Whi[wo];
        wln[ot] = *(const bf16x8*)&Wlo[wo];
      }
    }
#pragma unroll
    for (int ns = 0; ns < 4; ++ns) {
      u32x4 bw = (u32x4){rb[ns][0], rb[ns][1], rb[ns][2], rb[ns][3]};
      bf16x8 Bf = *(bf16x8*)&bw;
#pragma unroll
      for (int ot = 0; ot < 2; ++ot) {
        acc[ot][ns] = __builtin_amdgcn_mfma_f32_16x16x32_bf16(wh[ot], Bf, acc[ot][ns], 0, 0, 0);
        acc[ot][ns] = __builtin_amdgcn_mfma_f32_16x16x32_bf16(wl[ot], Bf, acc[ot][ns], 0, 0, 0);
      }
    }
#pragma unroll
    for (int ns = 0; ns < 4; ++ns)
#pragma unroll
      for (int i = 0; i < 4; ++i) rb[ns][i] = rbn[ns][i];
#pragma unroll
    for (int ot = 0; ot < 2; ++ot) { wh[ot] = whn[ot]; wl[ot] = wln[ot]; }
  }

#pragma unroll
  for (int ot = 0; ot < 2; ++ot)
#pragma unroll
    for (int r = 0; r < 4; ++r) {
      int o = ob + 16 * ot + 4 * g + r;
      float s = G[o] * rsqrtf(Vp[o] + EPSV);
      float sh = Bp[o] - Mp[o] * s;
#pragma unroll
      for (int ns = 0; ns < 4; ++ns) {
        int n = n0 + 16 * ns + ln;
        if (n < NTOK)
          out[((size_t)b * DIMC + o) * NTOK + n] = acc[ot][ns][r] * s + sh;
      }
    }
}

// ---------------------------------------------------------------------------
extern "C" void kernel_launch(void* const* d_in, const int* in_sizes, int n_in,
                              void* d_out, int out_size, void* d_ws, size_t ws_size,
                              hipStream_t stream) {
  const float* x      = (const float*)d_in[0];
  const float* qkv_w  = (const float*)d_in[1];
  const float* qkv_g  = (const float*)d_in[2];
  const float* qkv_b  = (const float*)d_in[3];
  const float* qkv_m  = (const float*)d_in[4];
  const float* qkv_v  = (const float*)d_in[5];
  const float* dw_w   = (const float*)d_in[6];
  const float* dw_g   = (const float*)d_in[7];
  const float* dw_b   = (const float*)d_in[8];
  const float* dw_m   = (const float*)d_in[9];
  const float* dw_v   = (const float*)d_in[10];
  const float* proj_w = (const float*)d_in[11];
  const float* proj_g = (const float*)d_in[12];
  const float* proj_b = (const float*)d_in[13];
  const float* proj_m = (const float*)d_in[14];
  const float* proj_v = (const float*)d_in[15];
  const float* rpb    = (const float*)d_in[16];
  const int*   rel    = (const int*)d_in[17];
  float* out = (float*)d_out;

  // ws layout (float units), ~52.1 MB total
  float* wsf  = (float*)d_ws;
  float*    biasM = wsf;                                       // 1,229,312 f
  float*    qb0  = biasM + (size_t)NH * MQ * NTOK * 4;         //   802,816 f
  float*    qb1  = qb0 + (size_t)BSZ * KD * NTOK;              //   802,816 f
  short*    kT0  = (short*)(qb1 + (size_t)BSZ * KD * NTOK);    // 1,835,008 sh
  short*    kT1  = kT0 + (size_t)BSZ * NPAD * 32;              // 1,835,008 sh
  short*    vb0  = kT1 + (size_t)BSZ * NPAD * 32;              // 1,835,008 sh
  short*    vb1  = vb0 + (size_t)BSZ * DV * NPAD;              // 1,835,008 sh
  unsigned* catB = (unsigned*)(vb1 + (size_t)BSZ * DV * NPAD); // 6,422,528 u32
  short*    Whi  = (short*)(catB + (size_t)BSZ * 128 * NTOK);  //    65,536 sh
  short*    Wlo  = Whi + (size_t)DIMC * DIMC;                  //    65,536 sh
  short*    Wqhi = Wlo + (size_t)DIMC * DIMC;                  //    16,384 sh
  short*    Wqlo = Wqhi + (size_t)NH * QKVO * CH;              //    16,384 sh

  k_prep<<<dim3(NB_BIAS + NB_WSP + NB_WSPQ + NB_QKV0), 256, 0, stream>>>(
      rpb, rel, biasM, proj_w, Whi, Wlo, qkv_w, Wqhi, Wqlo,
      x, qkv_g, qkv_b, qkv_m, qkv_v, qb0, kT0, vb0, kT1, vb1);

  for (int h = 0; h < NH; ++h) {
    float* qbC = (h & 1) ? qb1 : qb0;
    short* kTC = (h & 1) ? kT1 : kT0;
    short* vbC = (h & 1) ? vb1 : vb0;
    float* qbN = (h & 1) ? qb0 : qb1;
    short* kTN = (h & 1) ? kT0 : kT1;
    short* vbN = (h & 1) ? vb0 : vb1;
    k_head<<<dim3(3200), 256, 0, stream>>>(h, x, qbC, kTC, vbC, biasM,
        dw_w, dw_g, dw_b, dw_m, dw_v,
        Wqhi, Wqlo, qkv_g, qkv_b, qkv_m, qkv_v,
        catB, qbN, kTN, vbN);
  }

  k_proj7<<<dim3(1792), 256, 0, stream>>>(catB, Whi, Wlo, proj_g, proj_b,
                                          proj_m, proj_v, out);
}

// Round 18
// 356.997 us; speedup vs baseline: 1.6175x; 1.6175x over previous
//
#include <hip/hip_runtime.h>
#include <hip/hip_bf16.h>
#include <cstdint>
#include <cstddef>

// CascadeAttention MI355X — v17: v15 (360.8us, verified) + fused prep kernel
// ONLY. setprio removed — it perturbed wave scheduling enough to break the
// per-XCD L2 working-set residency (k_head FETCH 15.5->86MB, WRITE 25->171MB).

#define NH    8
#define KD    16
#define DV    32
#define CH    32
#define QKVO  64
#define DIMC  256
#define NTOK  392
#define NPAD  448
#define BSZ   128
#define EPSV  1e-5f
#define SCL2  0.3606737602222409f   // 0.25 * log2(e)
#define LOG2E 1.4426950408889634f
#define MQ    98                    // ceil(392/4)

// k_prep block-range bounds
#define NB_BIAS 4802                // 8*98*392*4 / 256
#define NB_WSP  256                 // 65536 / 256
#define NB_WSPQ 64                  // 16384 / 256
#define NB_QKV0 896                 // 7 * 128

typedef float f32x4 __attribute__((ext_vector_type(4)));
typedef short bf16x8 __attribute__((ext_vector_type(8)));
typedef unsigned int u32x4 __attribute__((ext_vector_type(4)));
typedef unsigned int u32x2 __attribute__((ext_vector_type(2)));

__device__ inline unsigned rne_bf16_bits(float x) {
  unsigned u = __float_as_uint(x);
  return (u + 0x7fffu + ((u >> 16) & 1u)) >> 16;
}
__device__ inline unsigned cvt_pk(float a, float b) {  // lo16=bf16(a), hi16=bf16(b)
  unsigned r;
  asm("v_cvt_pk_bf16_f32 %0, %1, %2" : "=v"(r) : "v"(a), "v"(b));
  return r;
}
__device__ inline float b2f_lo(unsigned w) { return __uint_as_float(w << 16); }
__device__ inline float b2f_hi(unsigned w) { return __uint_as_float(w & 0xffff0000u); }

// ---------------- fused prep: bias gather | W splits | head-0 qkv ----------
__global__ __launch_bounds__(256) void k_prep(
    const float* __restrict__ rpb, const int* __restrict__ rel,
    float* __restrict__ biasM,
    const float* __restrict__ Wp, short* __restrict__ Whi, short* __restrict__ Wlo,
    const float* __restrict__ Wq, short* __restrict__ Wqhi, short* __restrict__ Wqlo,
    const float* __restrict__ x, const float* __restrict__ G,
    const float* __restrict__ Bp, const float* __restrict__ Mp,
    const float* __restrict__ Vp,
    float* __restrict__ qb0, short* __restrict__ kT0, short* __restrict__ vb0,
    short* __restrict__ kT1, short* __restrict__ vb1) {
  int blk = blockIdx.x;
  int t = threadIdx.x;

  if (blk < NB_BIAS) {
    int idx = blk * 256 + t;
    if (idx >= NH * MQ * NTOK * 4) return;
    int j = idx & 3;
    int r1 = idx >> 2;
    int n = r1 % NTOK;
    int r2 = r1 / NTOK;
    int mq = r2 % MQ;
    int h = r2 / MQ;
    int m = min(4 * mq + j, NTOK - 1);
    biasM[idx] = rpb[rel[n * NTOK + m] * NH + h] * LOG2E;
    return;
  }
  if (blk < NB_BIAS + NB_WSP) {
    int i = (blk - NB_BIAS) * 256 + t;
    float v = Wp[i];
    unsigned u = __float_as_uint(v) & 0xffff0000u;
    Whi[i] = (short)(u >> 16);
    Wlo[i] = (short)rne_bf16_bits(v - __uint_as_float(u));
    return;
  }
  if (blk < NB_BIAS + NB_WSP + NB_WSPQ) {
    int i = (blk - NB_BIAS - NB_WSP) * 256 + t;
    float v = Wq[i];
    unsigned u = __float_as_uint(v) & 0xffff0000u;
    Wqhi[i] = (short)(u >> 16);
    Wqlo[i] = (short)rne_bf16_bits(v - __uint_as_float(u));
    return;
  }

  // ---- head-0 qkv + zero-init of ping-pong padding ----
  {
    int idq = blk - (NB_BIAS + NB_WSP + NB_WSPQ);
    int qt = idq % 7, b = idq / 7;
    int n = qt * 64 + (t & 63);
    int w = t >> 6;
    int o0 = __builtin_amdgcn_readfirstlane(w * 16);
    int nc = min(n, NTOK - 1);

    const float* xp = x + (size_t)b * DIMC * NTOK + nc;
    float f[CH];
#pragma unroll
    for (int c = 0; c < CH; ++c) f[c] = xp[(size_t)c * NTOK];

    float acc[16];
#pragma unroll
    for (int oi = 0; oi < 16; ++oi) acc[oi] = 0.f;
#pragma unroll
    for (int c = 0; c < CH; ++c) {
      float fv = f[c];
#pragma unroll
      for (int oi = 0; oi < 16; ++oi) acc[oi] += Wq[(o0 + oi) * CH + c] * fv;
    }
    float r[16];
#pragma unroll
    for (int oi = 0; oi < 16; ++oi) {
      int o = o0 + oi;
      float s = G[o] * rsqrtf(Vp[o] + EPSV);
      float sh = Bp[o] - Mp[o] * s;
      r[oi] = acc[oi] * s + sh;
    }

    if (w == 0) {
      if (n < NTOK) {
#pragma unroll
        for (int oi = 0; oi < 16; ++oi)
          qb0[((size_t)b * KD + oi) * NTOK + n] = r[oi];
      }
    } else if (w == 1) {
      unsigned wh[8], wl[8];
#pragma unroll
      for (int i = 0; i < 8; ++i) wh[i] = cvt_pk(r[2 * i], r[2 * i + 1]);
#pragma unroll
      for (int i = 0; i < 8; ++i)
        wl[i] = cvt_pk(r[2 * i] - b2f_lo(wh[i]), r[2 * i + 1] - b2f_hi(wh[i]));
      short* row = kT0 + ((size_t)b * NPAD + n) * 32;
      *(u32x4*)&row[0]  = (u32x4){wh[0], wh[1], wh[2], wh[3]};
      *(u32x4*)&row[8]  = (u32x4){wh[4], wh[5], wh[6], wh[7]};
      *(u32x4*)&row[16] = (u32x4){wl[0], wl[1], wl[2], wl[3]};
      *(u32x4*)&row[24] = (u32x4){wl[4], wl[5], wl[6], wl[7]};
      if (n >= NTOK) {
        short* row1 = kT1 + ((size_t)b * NPAD + n) * 32;
#pragma unroll
        for (int p = 0; p < 4; ++p) *(u32x4*)&row1[p * 8] = (u32x4){0, 0, 0, 0};
      }
    } else {
      int vc0 = (w - 2) * 16;
#pragma unroll
      for (int oi = 0; oi < 16; ++oi)
        vb0[((size_t)b * DV + vc0 + oi) * NPAD + n] = (short)rne_bf16_bits(r[oi]);
      if (n >= NTOK) {
#pragma unroll
        for (int oi = 0; oi < 16; ++oi)
          vb1[((size_t)b * DV + vc0 + oi) * NPAD + n] = 0;
      }
    }
  }
}

// ---------------- fused per-head kernel (XCD-swizzled 1-D grid) ------------
__global__ __launch_bounds__(256, 8) void k_head(int head,
    const float* __restrict__ x,
    const float* __restrict__ qbC, const short* __restrict__ kTC,
    const short* __restrict__ vbC, const float* __restrict__ biasM,
    const float* __restrict__ DW, const float* __restrict__ dG,
    const float* __restrict__ dB, const float* __restrict__ dM,
    const float* __restrict__ dV,
    const short* __restrict__ Wqhi, const short* __restrict__ Wqlo,
    const float* __restrict__ qG, const float* __restrict__ qBp,
    const float* __restrict__ qM, const float* __restrict__ qV,
    unsigned* __restrict__ catB, float* __restrict__ qbN,
    short* __restrict__ kTN, short* __restrict__ vbN) {
  __shared__ float wdw[432];
  __shared__ float qstage[16][17];
  __shared__ __align__(16) float ubuf[2304];  // halo[16][133] / Pbuf[4][576] / oP[4][32][17]
  __shared__ float lM[4][16];
  __shared__ float oF[32][17];
  __shared__ float xs[32][17];

  int t = threadIdx.x;
  int id = blockIdx.x;
  int r8 = id & 7;
  int jd = id >> 3;
  int qt = jd % 25;
  int b = 8 * (jd / 25) + r8;
  int w = t >> 6, l = t & 63;
  int ln = l & 15, g = l >> 4;
  int tok16 = t & 15, gr = t >> 4;
  int koff = ((g >> 1) << 4) + ((g & 1) << 3);

  // ---- phase A: stage dwconv weights + q halo, conv + BN + SCL2 ----
  {
    float (*hs)[133] = (float(*)[133])ubuf;
    for (int i = t; i < 432; i += 256) wdw[i] = DW[head * 432 + i];
    const float* qpb = qbC + (size_t)b * KD * NTOK;
    int nlo = qt * 16 - 57;
    for (int i = t; i < 16 * 130; i += 256) {
      int c = i / 130, r = i - c * 130;
      int n = nlo + r;
      hs[c][r] = (n >= 0 && n < NTOK) ? qpb[(size_t)c * NTOK + n] : 0.f;
    }
    __syncthreads();
    int tokg = qt * 16 + tok16;
    int tkc = min(tokg, NTOK - 1);
    int z = tkc / 49, rm = tkc - z * 49, y = rm / 7, xx = rm - y * 7;
    const float* wt = &wdw[gr * 27];
    float a = 0.f;
#pragma unroll
    for (int dz = 0; dz < 3; ++dz) {
      int zz = z + dz - 1;
      if (zz < 0 || zz >= 8) continue;
#pragma unroll
      for (int dy = 0; dy < 3; ++dy) {
        int yy = y + dy - 1;
        if (yy < 0 || yy >= 7) continue;
#pragma unroll
        for (int dx = 0; dx < 3; ++dx) {
          int xw = xx + dx - 1;
          if (xw < 0 || xw >= 7) continue;
          a += wt[dz * 9 + dy * 3 + dx] * hs[gr][zz * 49 + yy * 7 + xw - nlo];
        }
      }
    }
    float s = dG[head * KD + gr] * rsqrtf(dV[head * KD + gr] + EPSV);
    float sh = dB[head * KD + gr] - dM[head * KD + gr] * s;
    __syncthreads();            // all halo reads done before ubuf reuse
    qstage[gr][tok16] = (a * s + sh) * SCL2;
  }
  __syncthreads();

  // ---- Q fragments ----
  bf16x8 qB1, qB2;
  {
    float qv[8];
#pragma unroll
    for (int j2 = 0; j2 < 8; ++j2) qv[j2] = qstage[8 * (g & 1) + j2][ln];
    u32x4 hw;
#pragma unroll
    for (int i = 0; i < 4; ++i) hw[i] = cvt_pk(qv[2 * i], qv[2 * i + 1]);
    qB1 = *(bf16x8*)&hw;
    if (g < 2) {
      u32x4 lw;
#pragma unroll
      for (int i = 0; i < 4; ++i)
        lw[i] = cvt_pk(qv[2 * i] - b2f_lo(hw[i]), qv[2 * i + 1] - b2f_hi(hw[i]));
      qB2 = *(bf16x8*)&lw;
    } else {
#pragma unroll
      for (int j2 = 0; j2 < 8; ++j2) qB2[j2] = 0;
    }
  }

  int tokq = qt * 16 + ln;
  int tqc = min(tokq, NTOK - 1);
  const short* kbase = kTC + (size_t)b * NPAD * 32;
  const short* vbase = vbC + (size_t)b * DV * NPAD;
  const float* bb = biasM + ((size_t)head * MQ * NTOK + tqc) * 4;
  unsigned* pb = (unsigned*)ubuf + w * 576;

  f32x4 oacc[2];
#pragma unroll
  for (int ct = 0; ct < 2; ++ct) oacc[ct] = (f32x4){0.f, 0.f, 0.f, 0.f};
  float lsum = 0.f;

  // ---- phase B: attn over m-tiles {w, w+4} ----
  for (int mt = w; mt < 7; mt += 4) {
    int m0 = mt * 64;
    bf16x8 aK[4];
#pragma unroll
    for (int ms = 0; ms < 4; ++ms)
      aK[ms] = *(const bf16x8*)&kbase[(size_t)(m0 + 16 * ms + ln) * 32 + koff];
    f32x4 bv[4];
#pragma unroll
    for (int ms = 0; ms < 4; ++ms) {
      int mq = min((m0 + 16 * ms + 4 * g) >> 2, MQ - 1);
      bv[ms] = *(const f32x4*)&bb[(size_t)mq * (NTOK * 4)];
    }
    bf16x8 aV[4];
#pragma unroll
    for (int ch = 0; ch < 2; ++ch)
#pragma unroll
      for (int ct = 0; ct < 2; ++ct)
        aV[ch * 2 + ct] = *(const bf16x8*)&vbase[(size_t)(16 * ct + ln) * NPAD
                                                 + m0 + 32 * ch + 8 * g];
    f32x4 S[4];
#pragma unroll
    for (int ms = 0; ms < 4; ++ms) {
      f32x4 a = __builtin_amdgcn_mfma_f32_16x16x32_bf16(aK[ms], qB1, bv[ms], 0, 0, 0);
      S[ms] = __builtin_amdgcn_mfma_f32_16x16x32_bf16(aK[ms], qB2, a, 0, 0, 0);
    }
#pragma unroll
    for (int ms = 0; ms < 4; ++ms) {
      int mk = m0 + 16 * ms + 4 * g;
      float p[4];
#pragma unroll
      for (int r = 0; r < 4; ++r) {
        float sv = fminf(S[ms][r], 96.f);
        if (mk + r >= NTOK) sv = -1e30f;
        p[r] = __builtin_amdgcn_exp2f(sv);
        lsum += p[r];
      }
      u32x2 pw = (u32x2){cvt_pk(p[0], p[1]), cvt_pk(p[2], p[3])};
      *(u32x2*)&pb[ln * 36 + 8 * ms + 2 * g] = pw;
    }
#pragma unroll
    for (int ch = 0; ch < 2; ++ch) {
      u32x4 pk4 = *(const u32x4*)&pb[ln * 36 + 16 * ch + 4 * g];
      bf16x8 pf = *(bf16x8*)&pk4;
#pragma unroll
      for (int ct = 0; ct < 2; ++ct)
        oacc[ct] = __builtin_amdgcn_mfma_f32_16x16x32_bf16(aV[ch * 2 + ct], pf, oacc[ct], 0, 0, 0);
    }
  }

  // ---- phase C: partial reduce + merge (oP aliases ubuf -> sync first) ----
  __syncthreads();
  float (*oP)[32][17] = (float(*)[32][17])ubuf;
  lsum += __shfl_xor(lsum, 16);
  lsum += __shfl_xor(lsum, 32);
#pragma unroll
  for (int ct = 0; ct < 2; ++ct)
#pragma unroll
    for (int r = 0; r < 4; ++r) oP[w][16 * ct + 4 * g + r][ln] = oacc[ct][r];
  if (g == 0) lM[w][ln] = lsum;
  __syncthreads();

  // ---- phase D: finalize, catB store, x stage ----
  {
    int tokg = qt * 16 + tok16;
    float lt = lM[0][tok16] + lM[1][tok16] + lM[2][tok16] + lM[3][tok16];
    float inv = 1.f / fmaxf(lt, 1e-30f);
    int c0 = 2 * gr, c1 = c0 + 1;
    float a0 = (oP[0][c0][tok16] + oP[1][c0][tok16] + oP[2][c0][tok16] + oP[3][c0][tok16]) * inv;
    float a1 = (oP[0][c1][tok16] + oP[1][c1][tok16] + oP[2][c1][tok16] + oP[3][c1][tok16]) * inv;
    oF[c0][tok16] = a0;
    oF[c1][tok16] = a1;
    if (tokg < NTOK)
      catB[((size_t)b * 128 + head * 16 + gr) * NTOK + tokg] =
          cvt_pk(fmaxf(a0, 0.f), fmaxf(a1, 0.f));
    if (head < 7) {
      for (int i = t; i < 512; i += 256) {
        int c = i >> 4, tk = i & 15;
        int tg = min(qt * 16 + tk, NTOK - 1);
        xs[c][tk] = x[((size_t)b * DIMC + (head + 1) * CH + c) * NTOK + tg];
      }
    }
  }
  __syncthreads();

  // ---- phase E: next-head qkv via MFMA (3-term hi/lo) ----
  if (head < 7) {
    const short* wqh = Wqhi + ((size_t)(head + 1) * QKVO + 16 * w + ln) * CH + 8 * g;
    const short* wql = Wqlo + ((size_t)(head + 1) * QKVO + 16 * w + ln) * CH + 8 * g;
    bf16x8 Ah = *(const bf16x8*)wqh;
    bf16x8 Al = *(const bf16x8*)wql;
    float f8[8];
#pragma unroll
    for (int j2 = 0; j2 < 8; ++j2) f8[j2] = oF[8 * g + j2][ln] + xs[8 * g + j2][ln];
    u32x4 bh, blw;
#pragma unroll
    for (int i = 0; i < 4; ++i) {
      bh[i] = cvt_pk(f8[2 * i], f8[2 * i + 1]);
      blw[i] = cvt_pk(f8[2 * i] - b2f_lo(bh[i]), f8[2 * i + 1] - b2f_hi(bh[i]));
    }
    bf16x8 Bh = *(bf16x8*)&bh;
    bf16x8 Bl = *(bf16x8*)&blw;
    f32x4 acc = (f32x4){0.f, 0.f, 0.f, 0.f};
    acc = __builtin_amdgcn_mfma_f32_16x16x32_bf16(Ah, Bh, acc, 0, 0, 0);
    acc = __builtin_amdgcn_mfma_f32_16x16x32_bf16(Ah, Bl, acc, 0, 0, 0);
    acc = __builtin_amdgcn_mfma_f32_16x16x32_bf16(Al, Bh, acc, 0, 0, 0);
    float r4[4];
#pragma unroll
    for (int r = 0; r < 4; ++r) {
      int o = 16 * w + 4 * g + r;
      int idx = (head + 1) * QKVO + o;
      float s = qG[idx] * rsqrtf(qV[idx] + EPSV);
      float sh = qBp[idx] - qM[idx] * s;
      r4[r] = acc[r] * s + sh;
    }
    int tokg = qt * 16 + ln;
    if (tokg < NTOK) {
      if (w == 0) {             // q channels 4g..4g+3, fp32 [c][n]
#pragma unroll
        for (int r = 0; r < 4; ++r)
          qbN[((size_t)b * KD + 4 * g + r) * NTOK + tokg] = r4[r];
      } else if (w == 1) {      // k channels 4g..4g+3 -> packed row
        unsigned h0 = cvt_pk(r4[0], r4[1]), h1 = cvt_pk(r4[2], r4[3]);
        unsigned l0 = cvt_pk(r4[0] - b2f_lo(h0), r4[1] - b2f_hi(h0));
        unsigned l1 = cvt_pk(r4[2] - b2f_lo(h1), r4[3] - b2f_hi(h1));
        short* row = kTN + ((size_t)b * NPAD + tokg) * 32;
        *(u32x2*)&row[4 * g]      = (u32x2){h0, h1};
        *(u32x2*)&row[16 + 4 * g] = (u32x2){l0, l1};
      } else {                  // v channels 16(w-2)+4g..+3, bf16 [c][n]
        int vc0 = 16 * (w - 2) + 4 * g;
#pragma unroll
        for (int r = 0; r < 4; ++r)
          vbN[((size_t)b * DV + vc0 + r) * NPAD + tokg] = (short)rne_bf16_bits(r4[r]);
      }
    }
  }
}

// ---------------- proj: o-split (128 o x 64 n), XCD-pinned, dbuf -----------
__global__ __launch_bounds__(256, 4) void k_proj7(const unsigned* __restrict__ catB,
    const short* __restrict__ Whi, const short* __restrict__ Wlo,
    const float* __restrict__ G, const float* __restrict__ Bp,
    const float* __restrict__ Mp, const float* __restrict__ Vp,
    float* __restrict__ out) {
  int t = threadIdx.x;
  int id = blockIdx.x;
  int r8 = id & 7;
  int jd = id >> 3;
  int rem = jd % 14;
  int b = 8 * (jd / 14) + r8;
  int nt = rem >> 1, oh = rem & 1;
  int w = t >> 6, l = t & 63;
  int ln = l & 15, g = l >> 4;
  int n0 = nt * 64;
  int ob = oh * 128 + 32 * w;
  int ntk[4];
#pragma unroll
  for (int ns = 0; ns < 4; ++ns) ntk[ns] = min(n0 + 16 * ns + ln, NTOK - 1);
  const unsigned* xb = catB + (size_t)b * 128 * NTOK;

  f32x4 acc[2][4];
#pragma unroll
  for (int i = 0; i < 2; ++i)
#pragma unroll
    for (int j = 0; j < 4; ++j) acc[i][j] = (f32x4){0.f, 0.f, 0.f, 0.f};

  unsigned rb[4][4];
  bf16x8 wh[2], wl[2];
  {
#pragma unroll
    for (int ns = 0; ns < 4; ++ns)
#pragma unroll
      for (int i = 0; i < 4; ++i)
        rb[ns][i] = xb[(size_t)(4 * g + i) * NTOK + ntk[ns]];
#pragma unroll
    for (int ot = 0; ot < 2; ++ot) {
      size_t wo = (size_t)(ob + 16 * ot + ln) * DIMC + 8 * g;
      wh[ot] = *(const bf16x8*)&Whi[wo];
      wl[ot] = *(const bf16x8*)&Wlo[wo];
    }
  }

#pragma unroll 1
  for (int c8 = 0; c8 < 8; ++c8) {
    unsigned rbn[4][4];
    bf16x8 whn[2], wln[2];
    {
      int cpn = ((c8 + 1) & 7) * 16 + 4 * g;
#pragma unroll
      for (int ns = 0; ns < 4; ++ns)
#pragma unroll
        for (int i = 0; i < 4; ++i)
          rbn[ns][i] = xb[(size_t)(cpn + i) * NTOK + ntk[ns]];
      int cwn = ((c8 + 1) & 7) * 32 + 8 * g;
#pragma unroll
      for (int ot = 0; ot < 2; ++ot) {
        size_t wo = (size_t)(ob + 16 * ot + ln) * DIMC + cwn;
        whn[ot] = *(const bf16x8*)&Whi[wo];
        wln[ot] = *(const bf16x8*)&Wlo[wo];
      }
    }
#pragma unroll
    for (int ns = 0; ns < 4; ++ns) {
      u32x4 bw = (u32x4){rb[ns][0], rb[ns][1], rb[ns][2], rb[ns][3]};
      bf16x8 Bf = *(bf16x8*)&bw;
#pragma unroll
      for (int ot = 0; ot < 2; ++ot) {
        acc[ot][ns] = __builtin_amdgcn_mfma_f32_16x16x32_bf16(wh[ot], Bf, acc[ot][ns], 0, 0, 0);
        acc[ot][ns] = __builtin_amdgcn_mfma_f32_16x16x32_bf16(wl[ot], Bf, acc[ot][ns], 0, 0, 0);
      }
    }
#pragma unroll
    for (int ns = 0; ns < 4; ++ns)
#pragma unroll
      for (int i = 0; i < 4; ++i) rb[ns][i] = rbn[ns][i];
#pragma unroll
    for (int ot = 0; ot < 2; ++ot) { wh[ot] = whn[ot]; wl[ot] = wln[ot]; }
  }

#pragma unroll
  for (int ot = 0; ot < 2; ++ot)
#pragma unroll
    for (int r = 0; r < 4; ++r) {
      int o = ob + 16 * ot + 4 * g + r;
      float s = G[o] * rsqrtf(Vp[o] + EPSV);
      float sh = Bp[o] - Mp[o] * s;
#pragma unroll
      for (int ns = 0; ns < 4; ++ns) {
        int n = n0 + 16 * ns + ln;
        if (n < NTOK)
          out[((size_t)b * DIMC + o) * NTOK + n] = acc[ot][ns][r] * s + sh;
      }
    }
}

// ---------------------------------------------------------------------------
extern "C" void kernel_launch(void* const* d_in, const int* in_sizes, int n_in,
                              void* d_out, int out_size, void* d_ws, size_t ws_size,
                              hipStream_t stream) {
  const float* x      = (const float*)d_in[0];
  const float* qkv_w  = (const float*)d_in[1];
  const float* qkv_g  = (const float*)d_in[2];
  const float* qkv_b  = (const float*)d_in[3];
  const float* qkv_m  = (const float*)d_in[4];
  const float* qkv_v  = (const float*)d_in[5];
  const float* dw_w   = (const float*)d_in[6];
  const float* dw_g   = (const float*)d_in[7];
  const float* dw_b   = (const float*)d_in[8];
  const float* dw_m   = (const float*)d_in[9];
  const float* dw_v   = (const float*)d_in[10];
  const float* proj_w = (const float*)d_in[11];
  const float* proj_g = (const float*)d_in[12];
  const float* proj_b = (const float*)d_in[13];
  const float* proj_m = (const float*)d_in[14];
  const float* proj_v = (const float*)d_in[15];
  const float* rpb    = (const float*)d_in[16];
  const int*   rel    = (const int*)d_in[17];
  float* out = (float*)d_out;

  // ws layout (float units), ~52.1 MB total
  float* wsf  = (float*)d_ws;
  float*    biasM = wsf;                                       // 1,229,312 f
  float*    qb0  = biasM + (size_t)NH * MQ * NTOK * 4;         //   802,816 f
  float*    qb1  = qb0 + (size_t)BSZ * KD * NTOK;              //   802,816 f
  short*    kT0  = (short*)(qb1 + (size_t)BSZ * KD * NTOK);    // 1,835,008 sh
  short*    kT1  = kT0 + (size_t)BSZ * NPAD * 32;              // 1,835,008 sh
  short*    vb0  = kT1 + (size_t)BSZ * NPAD * 32;              // 1,835,008 sh
  short*    vb1  = vb0 + (size_t)BSZ * DV * NPAD;              // 1,835,008 sh
  unsigned* catB = (unsigned*)(vb1 + (size_t)BSZ * DV * NPAD); // 6,422,528 u32
  short*    Whi  = (short*)(catB + (size_t)BSZ * 128 * NTOK);  //    65,536 sh
  short*    Wlo  = Whi + (size_t)DIMC * DIMC;                  //    65,536 sh
  short*    Wqhi = Wlo + (size_t)DIMC * DIMC;                  //    16,384 sh
  short*    Wqlo = Wqhi + (size_t)NH * QKVO * CH;              //    16,384 sh

  k_prep<<<dim3(NB_BIAS + NB_WSP + NB_WSPQ + NB_QKV0), 256, 0, stream>>>(
      rpb, rel, biasM, proj_w, Whi, Wlo, qkv_w, Wqhi, Wqlo,
      x, qkv_g, qkv_b, qkv_m, qkv_v, qb0, kT0, vb0, kT1, vb1);

  for (int h = 0; h < NH; ++h) {
    float* qbC = (h & 1) ? qb1 : qb0;
    short* kTC = (h & 1) ? kT1 : kT0;
    short* vbC = (h & 1) ? vb1 : vb0;
    float* qbN = (h & 1) ? qb0 : qb1;
    short* kTN = (h & 1) ? kT0 : kT1;
    short* vbN = (h & 1) ? vb0 : vb1;
    k_head<<<dim3(3200), 256, 0, stream>>>(h, x, qbC, kTC, vbC, biasM,
        dw_w, dw_g, dw_b, dw_m, dw_v,
        Wqhi, Wqlo, qkv_g, qkv_b, qkv_m, qkv_v,
        catB, qbN, kTN, vbN);
  }

  k_proj7<<<dim3(1792), 256, 0, stream>>>(catB, Whi, Wlo, proj_g, proj_b,
                                          proj_m, proj_v, out);
}